// Round 5
// baseline (244.447 us; speedup 1.0000x reference)
//
#include <hip/hip_runtime.h>

#define F 256
#define TWO_F 512
#define BM 128
#define BN 64
#define BK 64
#define NBKT 512         // padded bucket count (real buckets: src>>7 -> 0..390)
#define EPB 8192         // edges per sort block (256 thr x 32)

typedef __attribute__((ext_vector_type(8))) short short8;
typedef __attribute__((ext_vector_type(4))) float float4v;

// ---------- bf16 helpers ----------
static __device__ __forceinline__ unsigned short f2bf(float f) {
    unsigned u = __float_as_uint(f);
    u += 0x7FFFu + ((u >> 16) & 1u);
    return (unsigned short)(u >> 16);
}
static __device__ __forceinline__ unsigned pack2(float lo, float hi) {
    unsigned a = __float_as_uint(lo) + 0x8000u;
    unsigned b = __float_as_uint(hi) + 0x8000u;
    return __builtin_amdgcn_perm(b, a, 0x07060302u);
}
static __device__ __forceinline__ float blo(unsigned u) { return __uint_as_float(u << 16); }
static __device__ __forceinline__ float rawf(unsigned u) { return __uint_as_float(u); }

// ---------- kernel 1 (merged prep): h fp32->hb bf16 and W1 fp32->Wb bf16, both k-rotated ----------
__global__ __launch_bounds__(256) void prep_kernel(
    const float* __restrict__ h, const float* __restrict__ W1,
    unsigned short* __restrict__ hb, unsigned short* __restrict__ Wb, int M)
{
    int i = blockIdx.x * blockDim.x + threadIdx.x;
    if (i < M * 128) {                       // h part: one bf16 pair per thread
        int m = i >> 7;
        int kp = (i & 127) * 2;
        float2 v = *(const float2*)(h + (size_t)m * F + kp);
        unsigned pk = pack2(v.x, v.y);
        int ksw = ((kp & 63) + (m & 7) * 8) & 63;
        *(unsigned*)(hb + (size_t)m * F + (kp & ~63) + ksw) = pk;
    }
    if (i < TWO_F * F) {                     // W part
        int n = i >> 8;
        int k = i & 255;
        float v = W1[(n & 255) * TWO_F + ((n >> 8) << 8) + k];
        int kin_sw = ((k & 63) + (n & 7) * 8) & 63;
        Wb[n * F + (k & ~63) + kin_sw] = f2bf(v);
    }
}

// ---------- kernel 2: C[m][n] = sum_k hb[m][k]*Wb[n][k] (+b1 for n<256), bf16 out ----------
// Barrier-free K-loop: A fragments loaded global->register directly (byte-identical to the
// old LDS path: per-row rotation in hb == (l15&7)*8 for each lane's own row). W panel
// (64x256, 32KB) staged in LDS once -> ONE barrier before the K-loop, none inside.
// Compiler can pipeline A-loads across the fully-unrolled 4 K-tiles (no vmcnt(0) drains).
// LDS 32KB -> 4 blocks/CU.
__global__ __launch_bounds__(256, 4) void gemm_kernel(
    const unsigned short* __restrict__ hb, const unsigned short* __restrict__ Wb,
    const float* __restrict__ b1v, unsigned short* __restrict__ C, int M)
{
    __shared__ unsigned short sB[BN * F];   // 32 KB full-K W panel; C-tile in epilogue

    // XCD pairing: all 8 by-blocks of one bx share (ib&7) -> same XCD -> hb strip L2-reused 8x.
    const int ib = blockIdx.x;
    const int r8 = ib & 7;
    const int q  = ib >> 3;
    const int by = q & 7;
    const int bx = (q >> 3) * 8 + r8;
    const int bm = bx * BM;
    if (bm >= M) return;
    const int bn = by * BN;

    const int tid  = threadIdx.x;
    const int lane = tid & 63;
    const int wid  = tid >> 6;
    const int quad = lane >> 4;
    const int l15  = lane & 15;
    const int rot  = (l15 & 7) * 8;

    // stage the whole W panel once: 8 issues x (256 thr x 16B = 4KB)
    #pragma unroll
    for (int p = 0; p < 8; ++p) {
        const unsigned short* gb = Wb + (size_t)(bn + p * 8 + (tid >> 5)) * F + (tid & 31) * 8;
        __builtin_amdgcn_global_load_lds(
            (const __attribute__((address_space(1))) unsigned int*)gb,
            (__attribute__((address_space(3))) unsigned int*)&sB[p * 2048 + tid * 8],
            16, 0, 0);
    }

    // per-lane A row pointers (clamped; clamped rows produce garbage but their stores are guarded)
    const unsigned short* arow[2];
    #pragma unroll
    for (int mt = 0; mt < 2; ++mt) {
        int am = bm + wid * 32 + mt * 16 + l15;
        if (am > M - 1) am = M - 1;
        arow[mt] = hb + (size_t)am * F;
    }

    float4v acc[2][4];
    #pragma unroll
    for (int i = 0; i < 2; ++i)
        #pragma unroll
        for (int j = 0; j < 4; ++j) acc[i][j] = (float4v)(0.f);

    __syncthreads();   // sB ready (drains the global_load_lds)

    #pragma unroll
    for (int kt = 0; kt < 4; ++kt) {
        #pragma unroll
        for (int ks = 0; ks < 2; ++ks) {
            const int koff = kt * 64 + ((ks * 32 + quad * 8 + rot) & 63);
            short8 afr[2], bfr[4];
            #pragma unroll
            for (int mt = 0; mt < 2; ++mt)
                afr[mt] = *(const short8*)(arow[mt] + koff);
            #pragma unroll
            for (int nt = 0; nt < 4; ++nt)
                bfr[nt] = *(const short8*)&sB[(nt * 16 + l15) * F + koff];
            #pragma unroll
            for (int mt = 0; mt < 2; ++mt)
                #pragma unroll
                for (int nt = 0; nt < 4; ++nt)
                    acc[mt][nt] = __builtin_amdgcn_mfma_f32_16x16x32_bf16(
                        afr[mt], bfr[nt], acc[mt][nt], 0, 0, 0);
        }
    }

    // epilogue: +b1 for the n<256 half, pack bf16 tile into sB (free now), coalesced stores
    float bias[4];
    #pragma unroll
    for (int nt = 0; nt < 4; ++nt) {
        int n = bn + nt * 16 + l15;
        bias[nt] = (n < F) ? b1v[n] : 0.f;
    }
    __syncthreads();   // all lanes done reading sB
    #pragma unroll
    for (int mt = 0; mt < 2; ++mt) {
        #pragma unroll
        for (int rr = 0; rr < 4; ++rr) {
            int row = wid * 32 + mt * 16 + quad * 4 + rr;
            #pragma unroll
            for (int nt = 0; nt < 4; ++nt)
                sB[row * BK + nt * 16 + l15] = f2bf(acc[mt][nt][rr] + bias[nt]);
        }
    }
    __syncthreads();
    #pragma unroll
    for (int p = 0; p < 4; ++p) {
        int row = p * 32 + (tid >> 3);
        int gm = bm + row;
        if (gm < M) {
            uint4 v = *(const uint4*)&sB[row * BK + (tid & 7) * 8];
            *(uint4*)(C + (size_t)gm * TWO_F + bn + (tid & 7) * 8) = v;
        }
    }
}

// ---------- edge sort: atomic-free 3-pass counting sort by src bucket (src>>7) ----------
__global__ __launch_bounds__(256) void sort_count_kernel(
    const int* __restrict__ src, int* __restrict__ counts, int E)
{
    __shared__ int cnt[NBKT];
    const int tid = threadIdx.x;
    #pragma unroll
    for (int i = tid; i < NBKT; i += 256) cnt[i] = 0;
    __syncthreads();
    const int base = blockIdx.x * EPB;
    #pragma unroll
    for (int j = 0; j < EPB / 256; ++j) {
        int e = base + j * 256 + tid;
        if (e < E) atomicAdd(&cnt[((unsigned)src[e]) >> 7], 1);   // LDS atomic only
    }
    __syncthreads();
    #pragma unroll
    for (int i = tid; i < NBKT; i += 256) counts[blockIdx.x * NBKT + i] = cnt[i];
}

__global__ __launch_bounds__(512) void sort_scan_kernel(
    int* __restrict__ counts, int* __restrict__ bucketbase, int nsb)
{
    __shared__ int s[NBKT];
    const int tid = threadIdx.x;
    int run = 0;
    int blk = 0;
    for (; blk + 8 <= nsb; blk += 8) {
        int v[8];
        #pragma unroll
        for (int u = 0; u < 8; ++u) v[u] = counts[(blk + u) * NBKT + tid];
        #pragma unroll
        for (int u = 0; u < 8; ++u) { counts[(blk + u) * NBKT + tid] = run; run += v[u]; }
    }
    for (; blk < nsb; ++blk) {
        int v = counts[blk * NBKT + tid];
        counts[blk * NBKT + tid] = run;
        run += v;
    }
    s[tid] = run;                       // bucket total
    __syncthreads();
    #pragma unroll
    for (int off = 1; off < NBKT; off <<= 1) {
        int x = (tid >= off) ? s[tid - off] : 0;
        __syncthreads();
        s[tid] += x;
        __syncthreads();
    }
    bucketbase[tid] = s[tid] - run;     // exclusive prefix over buckets
}

__global__ __launch_bounds__(256) void sort_scatter_kernel(
    const int* __restrict__ src, const int* __restrict__ dst,
    const int* __restrict__ counts, const int* __restrict__ bucketbase,
    int2* __restrict__ sort_sd, int* __restrict__ sort_idx, int E)
{
    __shared__ int cnt[NBKT];
    const int tid = threadIdx.x;
    #pragma unroll
    for (int i = tid; i < NBKT; i += 256) cnt[i] = 0;
    __syncthreads();
    const int base = blockIdx.x * EPB;
    #pragma unroll
    for (int j = 0; j < EPB / 256; ++j) {
        int e = base + j * 256 + tid;
        if (e < E) {
            int s = src[e];
            int b = ((unsigned)s) >> 7;
            int r = atomicAdd(&cnt[b], 1);                       // LDS atomic only
            int pos = bucketbase[b] + counts[blockIdx.x * NBKT + b] + r;
            sort_sd[pos] = make_int2(s, dst[e]);
            sort_idx[pos] = e;
        }
    }
}

// ---------- kernel 3: per-edge score over src-sorted edges, 2 edges per 32-lane group ----------
// XCD-contiguous swizzle: each XCD walks a contiguous span of sorted edges -> src rows
// near-sequential and L2/L1-resident.
__global__ __launch_bounds__(256) void edge_kernel(
    const unsigned short* __restrict__ C,
    const int2* __restrict__ sd, const int* __restrict__ sidx,
    const float* __restrict__ w2,
    const float* __restrict__ b2, float* __restrict__ out, int E)
{
    const int lane = threadIdx.x & 31;
    const int nblk = gridDim.x;
    const int ib = blockIdx.x;
    const int gb = (nblk & 7) == 0 ? ((ib & 7) * (nblk >> 3) + (ib >> 3)) : ib;
    const int g = gb * 8 + (threadIdx.x >> 5);
    const int e0 = g * 2;
    if (e0 >= E) return;
    const bool has1 = (e0 + 1 < E);
    int2 p0 = sd[e0];
    int2 p1 = has1 ? sd[e0 + 1] : p0;
    int i0 = sidx[e0];
    int i1 = has1 ? sidx[e0 + 1] : 0;

    uint4 av0 = *(const uint4*)(C + (size_t)p0.x * TWO_F + lane * 8);
    uint4 bv0 = *(const uint4*)(C + (size_t)p0.y * TWO_F + F + lane * 8);
    uint4 av1 = *(const uint4*)(C + (size_t)p1.x * TWO_F + lane * 8);
    uint4 bv1 = *(const uint4*)(C + (size_t)p1.y * TWO_F + F + lane * 8);
    float4 w0 = *(const float4*)(w2 + lane * 8);
    float4 w1 = *(const float4*)(w2 + lane * 8 + 4);

    float sum0, sum1;
    sum0  = w0.x * fmaxf(blo(av0.x) + blo(bv0.x), 0.f);
    sum0 += w0.y * fmaxf(rawf(av0.x) + rawf(bv0.x), 0.f);
    sum0 += w0.z * fmaxf(blo(av0.y) + blo(bv0.y), 0.f);
    sum0 += w0.w * fmaxf(rawf(av0.y) + rawf(bv0.y), 0.f);
    sum0 += w1.x * fmaxf(blo(av0.z) + blo(bv0.z), 0.f);
    sum0 += w1.y * fmaxf(rawf(av0.z) + rawf(bv0.z), 0.f);
    sum0 += w1.z * fmaxf(blo(av0.w) + blo(bv0.w), 0.f);
    sum0 += w1.w * fmaxf(rawf(av0.w) + rawf(bv0.w), 0.f);

    sum1  = w0.x * fmaxf(blo(av1.x) + blo(bv1.x), 0.f);
    sum1 += w0.y * fmaxf(rawf(av1.x) + rawf(bv1.x), 0.f);
    sum1 += w0.z * fmaxf(blo(av1.y) + blo(bv1.y), 0.f);
    sum1 += w0.w * fmaxf(rawf(av1.y) + rawf(bv1.y), 0.f);
    sum1 += w1.x * fmaxf(blo(av1.z) + blo(bv1.z), 0.f);
    sum1 += w1.y * fmaxf(rawf(av1.z) + rawf(bv1.z), 0.f);
    sum1 += w1.z * fmaxf(blo(av1.w) + blo(bv1.w), 0.f);
    sum1 += w1.w * fmaxf(rawf(av1.w) + rawf(bv1.w), 0.f);

    #pragma unroll
    for (int off = 16; off > 0; off >>= 1) {
        sum0 += __shfl_down(sum0, off, 32);
        sum1 += __shfl_down(sum1, off, 32);
    }

    if (lane == 0) {
        float b = b2[0];
        out[i0] = sum0 + b;
        if (has1) out[i1] = sum1 + b;
    }
}

extern "C" void kernel_launch(void* const* d_in, const int* in_sizes, int n_in,
                              void* d_out, int out_size, void* d_ws, size_t ws_size,
                              hipStream_t stream) {
    const float* h    = (const float*)d_in[0];
    const int*   src  = (const int*)d_in[1];
    const int*   dst  = (const int*)d_in[2];
    const float* W1_w = (const float*)d_in[3];
    const float* W1_b = (const float*)d_in[4];
    const float* W2_w = (const float*)d_in[5];
    const float* W2_b = (const float*)d_in[6];
    float* out = (float*)d_out;

    const int M = in_sizes[0] / F;   // 50000
    const int E = in_sizes[1];       // 800000

    // ws: [Wb 256KB][pad to 512KB][hb 25.6MB pad 26MB][C 51.2MB]
    // sort scratch overlays hb (dead after gemm): sd 6.4MB @+0, idx 3.2MB @+8MB,
    // counts 98*512*4=200KB @+12MB, bucketbase 2KB @+13MB.
    unsigned short* Wb = (unsigned short*)d_ws;
    unsigned short* hb = (unsigned short*)((char*)d_ws + 512 * 1024);
    unsigned short* C  = (unsigned short*)((char*)d_ws + 512 * 1024 + 26 * 1024 * 1024);
    int2* sort_sd    = (int2*)hb;
    int*  sort_idx   = (int*)((char*)hb + 8 * 1024 * 1024);
    int*  counts     = (int*)((char*)hb + 12 * 1024 * 1024);
    int*  bucketbase = (int*)((char*)hb + 13 * 1024 * 1024);

    // merged prep
    int prep_threads = M * 128 > TWO_F * F ? M * 128 : TWO_F * F;
    prep_kernel<<<(prep_threads + 255) / 256, 256, 0, stream>>>(h, W1_w, hb, Wb, M);

    // gemm: 392 m-chunks x 8 n-blocks, XCD-paired encoding
    int nbx = ((M + BM - 1) / BM + 7) / 8 * 8;     // 392
    gemm_kernel<<<nbx * 8, 256, 0, stream>>>(hb, Wb, W1_b, C, M);

    // atomic-free counting sort by src bucket (scratch overlays hb after gemm; no memset needed)
    int nsb = (E + EPB - 1) / EPB;                 // 98
    sort_count_kernel<<<nsb, 256, 0, stream>>>(src, counts, E);
    sort_scan_kernel<<<1, 512, 0, stream>>>(counts, bucketbase, nsb);
    sort_scatter_kernel<<<nsb, 256, 0, stream>>>(src, dst, counts, bucketbase, sort_sd, sort_idx, E);

    // edge scoring over sorted edges
    int eblocks = (E / 2 + 7) / 8;                 // 50000
    edge_kernel<<<eblocks, 256, 0, stream>>>(C, sort_sd, sort_idx, W2_w, W2_b, out, E);
}